// Round 9
// baseline (467.777 us; speedup 1.0000x reference)
//
#include <hip/hip_runtime.h>

#define D 128
#define BSHIFT 8
#define BSIZE 256        // nodes per fine bucket
#define NBMAX 512        // max buckets (N <= 131072)
#define CHUNK 4096       // edges per block in scatter
#define SRCBITS 17
#define SRCMASK 0x1FFFF

typedef unsigned int uint;
typedef unsigned short u16;
typedef unsigned char u8;
typedef __attribute__((ext_vector_type(8))) short short8;
typedef __attribute__((ext_vector_type(4))) float floatx4;

// ---- bf16 helpers (RNE) ----
__device__ __forceinline__ u16 f2bf(float f) {
    union { float f; uint u; } c; c.f = f;
    uint u = c.u;
    u += 0x7FFFu + ((u >> 16) & 1u);
    return (u16)(u >> 16);
}
__device__ __forceinline__ float bflo(uint u) {
    union { uint u; float f; } c; c.u = u << 16; return c.f;
}
__device__ __forceinline__ float bfhi(uint u) {
    union { uint u; float f; } c; c.u = u & 0xFFFF0000u; return c.f;
}
__device__ __forceinline__ void add8(float* acc, uint4 v) {
    acc[0] += bflo(v.x); acc[1] += bfhi(v.x);
    acc[2] += bflo(v.y); acc[3] += bfhi(v.y);
    acc[4] += bflo(v.z); acc[5] += bfhi(v.z);
    acc[6] += bflo(v.w); acc[7] += bfhi(v.w);
}

// ------- setup: W1/W2 transpose+convert, cursor init (one launch) ----------
__global__ __launch_bounds__(256) void setup_kernel(
    const float* __restrict__ W1, const float* __restrict__ W2,
    u16* __restrict__ wT1, u16* __restrict__ wT2,
    int* __restrict__ cursor_d, int* __restrict__ cursor_s, int NB, int cap)
{
    int b = blockIdx.x, t = threadIdx.x;
    if (b < 64) {
        int i = b * 256 + t;                 // i = k*128 + n
        int k = i >> 7, n = i & 127;
        wT1[n * 128 + k] = f2bf(W1[i]);
    } else if (b < 128) {
        int i = (b - 64) * 256 + t;
        int k = i >> 7, n = i & 127;
        wT2[n * 128 + k] = f2bf(W2[i]);
    } else {
        for (int j = t; j < NB; j += 256) {
            cursor_d[j] = j * cap;
            cursor_s[j] = j * cap;
        }
    }
}

// ------- single edge pass, NO per-edge global atomics ----------------------
__global__ __launch_bounds__(256) void scatter_direct_kernel(
    const int* __restrict__ src, const int* __restrict__ dst,
    int* __restrict__ cursor_d, int* __restrict__ cursor_s,
    int* __restrict__ packed, u8* __restrict__ sbytes, int E, int cap)
{
    __shared__ int lcnt_d[NBMAX], lbase_d[NBMAX];
    __shared__ int lcnt_s[NBMAX], lbase_s[NBMAX];
    __shared__ int dbuf[CHUNK];      // 16 KB dst cache: read global once
    __shared__ int sbuf[CHUNK];      // 16 KB src cache: read global once
    int t = threadIdx.x;
    for (int j = t; j < NBMAX; j += 256) { lcnt_d[j] = 0; lcnt_s[j] = 0; }
    __syncthreads();
    int base = blockIdx.x * CHUNK;
    int end  = min(base + CHUNK, E);
    for (int i = base + t; i < end; i += 256) {
        int d = dst[i];
        int s = src[i];
        dbuf[i - base] = d;
        sbuf[i - base] = s;
        atomicAdd(&lcnt_d[d >> BSHIFT], 1);
        atomicAdd(&lcnt_s[s >> BSHIFT], 1);
    }
    __syncthreads();
    int rot = (blockIdx.x * 97) & (NBMAX - 1);
    for (int j = t; j < NBMAX; j += 256) {
        int jj = (j + rot) & (NBMAX - 1);
        int c = lcnt_d[jj];
        lbase_d[jj] = c ? atomicAdd(&cursor_d[jj], c) : 0;
        lcnt_d[jj] = 0;
        c = lcnt_s[jj];
        lbase_s[jj] = c ? atomicAdd(&cursor_s[jj], c) : 0;
        lcnt_s[jj] = 0;
    }
    __syncthreads();
    for (int i = base + t; i < end; i += 256) {
        int d = dbuf[i - base];
        int s = sbuf[i - base];
        int bd = d >> BSHIFT;
        int slot = lbase_d[bd] + atomicAdd(&lcnt_d[bd], 1);
        if (slot < (bd + 1) * cap)           // overflow guard (cap = 2x mean)
            packed[slot] = ((d & (BSIZE - 1)) << SRCBITS) | s;
        int bs = s >> BSHIFT;
        int slot2 = lbase_s[bs] + atomicAdd(&lcnt_s[bs], 1);
        if (slot2 < (bs + 1) * cap)
            sbytes[slot2] = (u8)(s & (BSIZE - 1));
    }
}

// ------- scan dst-bucket counts (one small block) --------------------------
__global__ __launch_bounds__(NBMAX) void bucket_scan_kernel(
    const int* __restrict__ cursor, int* __restrict__ bucket_ptr,
    int* __restrict__ row_ptr, int NB, int N, int E, int cap)
{
    __shared__ int sh[NBMAX];
    int t = threadIdx.x;
    int c = (t < NB) ? min(cursor[t] - t * cap, cap) : 0;
    sh[t] = c;
    __syncthreads();
    for (int off = 1; off < NBMAX; off <<= 1) {
        int v = (t >= off) ? sh[t - off] : 0;
        __syncthreads();
        sh[t] += v;
        __syncthreads();
    }
    if (t < NB) bucket_ptr[t] = sh[t] - c;   // exclusive prefix
    if (t == 0) row_ptr[N] = E;
}

// ------- fused per-bucket: fine CSR + src hist + PRE-SCALED feat convert ---
__global__ __launch_bounds__(256) void fine_place_kernel(
    const int* __restrict__ packed, const u8* __restrict__ sbytes,
    const int* __restrict__ cursor_d, const int* __restrict__ cursor_s,
    const int* __restrict__ bucket_ptr, int* __restrict__ row_ptr,
    float* __restrict__ norm_dst, float* __restrict__ norm_src,
    int* __restrict__ col,
    const float* __restrict__ feat, u16* __restrict__ feat_bf,
    int N, int cap)
{
    __shared__ int lcnt[BSIZE];
    __shared__ int lptr[BSIZE];
    __shared__ uint hist[BSIZE];
    int b = blockIdx.x, t = threadIdx.x;
    int nbase = b << BSHIFT;
    int pbase = b * cap;
    int cnt   = min(cursor_d[b] - pbase, cap);
    int scnt  = min(cursor_s[b] - pbase, cap);
    int obase = bucket_ptr[b];
    lcnt[t] = 0;
    hist[t] = 0;
    __syncthreads();
    for (int i = t; i < cnt; i += 256)
        atomicAdd(&lcnt[packed[pbase + i] >> SRCBITS], 1);
    // src-degree histogram from byte bucket (uint4-packed reads)
    {
        const uint* w = (const uint*)(sbytes + pbase);  // cap mult of 1024 -> aligned
        int nw = scnt >> 2;
        for (int i = t; i < nw; i += 256) {
            uint v = w[i];
            atomicAdd(&hist[v & 255u], 1u);
            atomicAdd(&hist[(v >> 8) & 255u], 1u);
            atomicAdd(&hist[(v >> 16) & 255u], 1u);
            atomicAdd(&hist[v >> 24], 1u);
        }
        for (int i = (nw << 2) + t; i < scnt; i += 256)
            atomicAdd(&hist[sbytes[pbase + i]], 1u);
    }
    __syncthreads();
    for (int off = 1; off < BSIZE; off <<= 1) {
        int v = (t >= off) ? lcnt[t - off] : 0;
        __syncthreads();
        lcnt[t] += v;
        __syncthreads();
    }
    {
        int incl = lcnt[t];
        int excl = (t == 0) ? 0 : lcnt[t - 1];
        int node = nbase + t;
        if (node < N) {
            row_ptr[node] = obase + excl;
            norm_dst[node] = rsqrtf((float)max(incl - excl, 1));
            norm_src[node] = rsqrtf((float)max((int)hist[t], 1));
        }
        lptr[t] = obase + excl;
    }
    __syncthreads();
    for (int i = t; i < cnt; i += 256) {
        int p = packed[pbase + i];
        int slot = atomicAdd(&lptr[p >> SRCBITS], 1);
        col[slot] = p & SRCMASK;
    }
    // ---- feature fp32 -> bf16, pre-scaled by norm_src (hist is local) ----
    {
        const float4* f4 = (const float4*)feat;
        for (int e = t; e < BSIZE * 32; e += 256) {
            int row = e >> 5;
            int node = nbase + row;
            if (node < N) {
                float ns = rsqrtf((float)max((int)hist[row], 1));
                float4 v = f4[(size_t)node * 32 + (e & 31)];
                ushort4 o;
                o.x = f2bf(v.x * ns); o.y = f2bf(v.y * ns);
                o.z = f2bf(v.z * ns); o.w = f2bf(v.w * ns);
                ((ushort4*)feat_bf)[(size_t)node * 32 + (e & 31)] = o;
            }
        }
    }
}

// ---------- FUSED, BARRIER-FREE, SAME PARALLELISM AS r7 --------------------
// Grid = N/16 blocks x 4 waves (25K waves, 4 nodes each - the proven 84us
// parallelism level). Each wave is fully self-contained: gathers its 4 rows
// into a wave-private LDS tile, then MFMAs a 16x128 A-tile whose rows are
// duplicates (row m16&3) - output rows 4-15 discarded (MfmaUtil is 1.5%,
// the 4x redundancy is free). ZERO __syncthreads: no max-of-16 straggler,
// each wave's MFMA/epilogue overlaps other waves' gathers. Per-col-tile
// accumulator (4 VGPR) + separate LDS out-tile (input tile must stay intact
// through the whole c-loop) keeps VGPR ~40 -> 8 blocks/CU.
template <bool BF16_OUT>
__global__ __launch_bounds__(256) void agg_gemm_kernel(
    const u16* __restrict__ hs, const int* __restrict__ row_ptr,
    const int* __restrict__ col, const float* __restrict__ norm_src,
    const float* __restrict__ norm_dst, const u16* __restrict__ WT,
    const float* __restrict__ bias, float* __restrict__ out_f,
    u16* __restrict__ out_b, int N)
{
    __shared__ u16 rows[4][4][144];   // wave-private A rows (stride 288B)
    __shared__ u16 outw[4][4][136];   // wave-private bf16 out tile
    int wave = threadIdx.x >> 6;
    int lane = threadIdx.x & 63;
    int g    = lane >> 4;     // edge-group 0..3 (gather); quad (MFMA)
    int l16  = lane & 15;     // row position (gather); m16 (MFMA)
    int wbase = blockIdx.x * 16 + wave * 4;   // this wave's 4 rows
    const uint4* h4 = (const uint4*)hs;
    u16 (*rw)[144] = rows[wave];
    u16 (*ow)[136] = outw[wave];

    // ---- gather: 4 nodes, 4 edges/group in flight (r7-proven loop) --------
    #pragma unroll
    for (int j = 0; j < 4; ++j) {
        int n = wbase + j;
        float acc[8];
        #pragma unroll
        for (int k = 0; k < 8; ++k) acc[k] = 0.f;

        if (n < N) {
            int beg = row_ptr[n], end = row_ptr[n + 1];
            int i = beg + g;
            for (; i + 12 < end; i += 16) {       // 4 rows in flight
                int s0 = col[i], s1 = col[i + 4], s2 = col[i + 8], s3 = col[i + 12];
                uint4 v0 = h4[(size_t)s0 * 16 + l16];
                uint4 v1 = h4[(size_t)s1 * 16 + l16];
                uint4 v2 = h4[(size_t)s2 * 16 + l16];
                uint4 v3 = h4[(size_t)s3 * 16 + l16];
                add8(acc, v0); add8(acc, v1); add8(acc, v2); add8(acc, v3);
            }
            for (; i + 4 < end; i += 8) {         // 2 rows in flight
                int s0 = col[i], s1 = col[i + 4];
                uint4 v0 = h4[(size_t)s0 * 16 + l16];
                uint4 v1 = h4[(size_t)s1 * 16 + l16];
                add8(acc, v0); add8(acc, v1);
            }
            if (i < end) {
                int s = col[i];
                uint4 v = h4[(size_t)s * 16 + l16];
                add8(acc, v);
            }
        }

        #pragma unroll
        for (int k = 0; k < 8; ++k) {
            acc[k] += __shfl_xor(acc[k], 16, 64);
            acc[k] += __shfl_xor(acc[k], 32, 64);
        }

        if (g == 0) {
            float nd = (n < N) ? norm_dst[n] : 0.f;
            ushort4 lo, hi;
            lo.x = f2bf(acc[0] * nd); lo.y = f2bf(acc[1] * nd);
            lo.z = f2bf(acc[2] * nd); lo.w = f2bf(acc[3] * nd);
            hi.x = f2bf(acc[4] * nd); hi.y = f2bf(acc[5] * nd);
            hi.z = f2bf(acc[6] * nd); hi.w = f2bf(acc[7] * nd);
            ushort4* o = (ushort4*)&rw[j][l16 * 8];
            o[0] = lo; o[1] = hi;
        }
    }
    // wave-local LDS: writes visible to same wave after lgkmcnt (compiler-
    // inserted); no cross-wave data flow anywhere -> no barrier.

    // ---- MFMA: A rows = duplicates of rows 0-3 (row m16&3); per-c acc -----
    int m16 = l16, quad = g;
    int arow = m16 & 3;
    float ns[4];
    if (BF16_OUT) {
        #pragma unroll
        for (int r = 0; r < 4; ++r) {
            int row = wbase + r;
            ns[r] = (row < N) ? norm_src[row] : 0.f;
        }
    }
    #pragma unroll
    for (int c = 0; c < 8; ++c) {
        floatx4 accm = (floatx4){0.f, 0.f, 0.f, 0.f};
        #pragma unroll
        for (int q = 0; q < 4; ++q) {
            short8 a = *(const short8*)&rw[arow][q * 32 + quad * 8];
            short8 b = *(const short8*)(WT + (size_t)(c * 16 + m16) * D + q * 32 + quad * 8);
            accm = __builtin_amdgcn_mfma_f32_16x16x32_bf16(a, b, accm, 0, 0, 0);
        }
        // D layout: row = quad*4+reg, col = m16 -> only quad==0 rows valid
        if (quad == 0) {
            float bv = bias[c * 16 + m16];
            if (BF16_OUT) {
                #pragma unroll
                for (int r = 0; r < 4; ++r)
                    ow[r][c * 16 + m16] = f2bf(fmaxf(accm[r] + bv, 0.f) * ns[r]);
            } else {
                // 16 lanes x 4B consecutive cols = 64B runs; full tile over c
                #pragma unroll
                for (int r = 0; r < 4; ++r) {
                    int row = wbase + r;
                    if (row < N)
                        out_f[(size_t)row * D + c * 16 + m16] = fmaxf(accm[r] + bv, 0.f);
                }
            }
        }
    }

    if (BF16_OUT) {
        // coalesced store of the wave's 4x128 bf16 tile: 256B/row bursts
        int r = g;                      // 0..3
        int row = wbase + r;
        if (row < N) {
            ushort4 a0 = *(const ushort4*)&ow[r][l16 * 8];
            ushort4 a1 = *(const ushort4*)&ow[r][l16 * 8 + 4];
            ushort4* o = (ushort4*)(out_b + (size_t)row * D + l16 * 8);
            o[0] = a0; o[1] = a1;
        }
    }
}

extern "C" void kernel_launch(void* const* d_in, const int* in_sizes, int n_in,
                              void* d_out, int out_size, void* d_ws, size_t ws_size,
                              hipStream_t stream)
{
    const float* features = (const float*)d_in[0];
    const int*   src      = (const int*)d_in[1];
    const int*   dst      = (const int*)d_in[2];
    const float* W1       = (const float*)d_in[3];
    const float* b1       = (const float*)d_in[4];
    const float* W2       = (const float*)d_in[5];
    const float* b2       = (const float*)d_in[6];
    float*       out      = (float*)d_out;

    const int N = in_sizes[0] / D;
    const int E = in_sizes[1];
    const int NB = (N + BSIZE - 1) >> BSHIFT;

    // padded bucket capacity: 2x mean, multiple of 1024;
    // bounded so packed(4B) + sbytes(1B) fit the N*D bf16 region (5B/slot).
    int cap = ((2 * (E / NB) + 2047) / 1024) * 1024;
    int cap_max = (int)(((size_t)N * D * 2 / (5 * NB)) / 1024 * 1024);
    if (cap > cap_max) cap = cap_max;

    // workspace layout
    u16*   scratch  = (u16*)d_ws;                   // N*D bf16 region (packed+sbytes)
    int*   packed   = (int*)scratch;                // NB*cap ints
    u8*    sbytes   = (u8*)(packed + (size_t)NB * cap);  // NB*cap bytes
    u16*   feat_bf  = scratch + (size_t)N * D;      // N*D bf16
    u16*   hs_bf    = feat_bf + (size_t)N * D;      // N*D bf16
    u16*   wT1      = hs_bf + (size_t)N * D;        // 16384 bf16
    u16*   wT2      = wT1 + D * D;                  // 16384 bf16
    float* norm_src = (float*)(wT2 + D * D);        // N
    float* norm_dst = norm_src + N;                 // N
    int*   iws          = (int*)(norm_dst + N);
    int*   row_ptr      = iws;                      // N+1
    int*   col          = row_ptr + N + 1;          // E
    int*   bucket_ptr   = col + E;                  // NBMAX+1
    int*   cursor_d     = bucket_ptr + NBMAX + 1;   // NBMAX
    int*   cursor_s     = cursor_d + NBMAX;         // NBMAX

    const int ebk = (E + CHUNK - 1) / CHUNK;
    const int fuse_blocks = (N + 15) / 16;

    // ---- CSR build: 4 launches total before the fused layers ----
    setup_kernel<<<129, 256, 0, stream>>>(W1, W2, wT1, wT2, cursor_d, cursor_s, NB, cap);
    scatter_direct_kernel<<<ebk, 256, 0, stream>>>(src, dst, cursor_d, cursor_s, packed, sbytes, E, cap);
    bucket_scan_kernel<<<1, NBMAX, 0, stream>>>(cursor_d, bucket_ptr, row_ptr, NB, N, E, cap);
    fine_place_kernel<<<NB, 256, 0, stream>>>(
        packed, sbytes, cursor_d, cursor_s, bucket_ptr, row_ptr,
        norm_dst, norm_src, col, features, feat_bf, N, cap);

    // ---- layer 1 (fused aggregate+GEMM, bf16 out pre-scaled by norm_src) ----
    agg_gemm_kernel<true><<<fuse_blocks, 256, 0, stream>>>(
        feat_bf, row_ptr, col, norm_src, norm_dst, wT1, b1, nullptr, hs_bf, N);

    // ---- layer 2 (fused aggregate+GEMM, f32 out) ----
    agg_gemm_kernel<false><<<fuse_blocks, 256, 0, stream>>>(
        hs_bf, row_ptr, col, norm_src, norm_dst, wT2, b2, out, nullptr, N);
}

// Round 10
// 360.303 us; speedup vs baseline: 1.2983x; 1.2983x over previous
//
#include <hip/hip_runtime.h>

#define D 128
#define BSHIFT 8
#define BSIZE 256        // nodes per fine bucket
#define NBMAX 512        // max buckets (N <= 131072)
#define CHUNK 8192       // edges per block in scatter (8KB LDS only)
#define SRCBITS 17
#define SRCMASK 0x1FFFF

typedef unsigned int uint;
typedef unsigned short u16;
typedef unsigned char u8;
typedef __attribute__((ext_vector_type(8))) short short8;
typedef __attribute__((ext_vector_type(4))) float floatx4;

// ---- bf16 helpers (RNE) ----
__device__ __forceinline__ u16 f2bf(float f) {
    union { float f; uint u; } c; c.f = f;
    uint u = c.u;
    u += 0x7FFFu + ((u >> 16) & 1u);
    return (u16)(u >> 16);
}
__device__ __forceinline__ float bflo(uint u) {
    union { uint u; float f; } c; c.u = u << 16; return c.f;
}
__device__ __forceinline__ float bfhi(uint u) {
    union { uint u; float f; } c; c.u = u & 0xFFFF0000u; return c.f;
}
__device__ __forceinline__ void add8(float* acc, uint4 v) {
    acc[0] += bflo(v.x); acc[1] += bfhi(v.x);
    acc[2] += bflo(v.y); acc[3] += bfhi(v.y);
    acc[4] += bflo(v.z); acc[5] += bfhi(v.z);
    acc[6] += bflo(v.w); acc[7] += bfhi(v.w);
}

// ------- setup: W transpose+convert, cursor init, row_ptr[N]=E -------------
__global__ __launch_bounds__(256) void setup_kernel(
    const float* __restrict__ W1, const float* __restrict__ W2,
    u16* __restrict__ wT1, u16* __restrict__ wT2,
    int* __restrict__ cursor_d, int* __restrict__ cursor_s,
    int* __restrict__ row_ptr, int NB, int N, int E, int cap)
{
    int b = blockIdx.x, t = threadIdx.x;
    if (b < 64) {
        int i = b * 256 + t;                 // i = k*128 + n
        int k = i >> 7, n = i & 127;
        wT1[n * 128 + k] = f2bf(W1[i]);
    } else if (b < 128) {
        int i = (b - 64) * 256 + t;
        int k = i >> 7, n = i & 127;
        wT2[n * 128 + k] = f2bf(W2[i]);
    } else {
        for (int j = t; j < NB; j += 256) {
            cursor_d[j] = j * cap;
            cursor_s[j] = j * cap;
        }
        if (t == 0) row_ptr[N] = E;
    }
}

// ------- single edge pass, NO per-edge global atomics, NO LDS staging ------
// Pass 1: LDS histograms only (2 atomics/edge). Alloc: batched cursor grabs.
// Pass 2: re-read src/dst (coalesced, L2-hot) and place. LDS = 8KB.
__global__ __launch_bounds__(256) void scatter_direct_kernel(
    const int* __restrict__ src, const int* __restrict__ dst,
    int* __restrict__ cursor_d, int* __restrict__ cursor_s,
    int* __restrict__ packed, u8* __restrict__ sbytes, int E, int cap)
{
    __shared__ int lcnt_d[NBMAX], lbase_d[NBMAX];
    __shared__ int lcnt_s[NBMAX], lbase_s[NBMAX];
    int t = threadIdx.x;
    for (int j = t; j < NBMAX; j += 256) { lcnt_d[j] = 0; lcnt_s[j] = 0; }
    __syncthreads();
    int base = blockIdx.x * CHUNK;
    int end  = min(base + CHUNK, E);
    for (int i = base + t; i < end; i += 256) {
        atomicAdd(&lcnt_d[dst[i] >> BSHIFT], 1);
        atomicAdd(&lcnt_s[src[i] >> BSHIFT], 1);
    }
    __syncthreads();
    int rot = (blockIdx.x * 97) & (NBMAX - 1);
    for (int j = t; j < NBMAX; j += 256) {
        int jj = (j + rot) & (NBMAX - 1);
        int c = lcnt_d[jj];
        lbase_d[jj] = c ? atomicAdd(&cursor_d[jj], c) : 0;
        lcnt_d[jj] = 0;
        c = lcnt_s[jj];
        lbase_s[jj] = c ? atomicAdd(&cursor_s[jj], c) : 0;
        lcnt_s[jj] = 0;
    }
    __syncthreads();
    for (int i = base + t; i < end; i += 256) {
        int d = dst[i];
        int s = src[i];
        int bd = d >> BSHIFT;
        int slot = lbase_d[bd] + atomicAdd(&lcnt_d[bd], 1);
        if (slot < (bd + 1) * cap)           // overflow guard (cap = 2x mean)
            packed[slot] = ((d & (BSIZE - 1)) << SRCBITS) | s;
        int bs = s >> BSHIFT;
        int slot2 = lbase_s[bs] + atomicAdd(&lcnt_s[bs], 1);
        if (slot2 < (bs + 1) * cap)
            sbytes[slot2] = (u8)(s & (BSIZE - 1));
    }
}

// ------- fused per-bucket: in-block bucket scan + fine CSR + src hist +
//         PRE-SCALED feat convert (bucket_scan kernel folded in) ------------
__global__ __launch_bounds__(256) void fine_place_kernel(
    const int* __restrict__ packed, const u8* __restrict__ sbytes,
    const int* __restrict__ cursor_d, const int* __restrict__ cursor_s,
    int* __restrict__ row_ptr,
    float* __restrict__ norm_dst, float* __restrict__ norm_src,
    int* __restrict__ col,
    const float* __restrict__ feat, u16* __restrict__ feat_bf,
    int NB, int N, int cap)
{
    __shared__ int lcnt[BSIZE];
    __shared__ int lptr[BSIZE];
    __shared__ uint hist[BSIZE];
    __shared__ int obase_s;
    int b = blockIdx.x, t = threadIdx.x;
    int nbase = b << BSHIFT;
    int pbase = b * cap;
    int cnt   = min(cursor_d[b] - pbase, cap);
    int scnt  = min(cursor_s[b] - pbase, cap);
    lcnt[t] = 0;
    hist[t] = 0;
    if (t == 0) obase_s = 0;
    __syncthreads();
    // in-block exclusive bucket prefix: obase = sum_{j<b} cnt_j
    {
        int partial = 0;
        for (int j = t; j < b; j += 256)
            partial += min(cursor_d[j] - j * cap, cap);
        if (partial) atomicAdd(&obase_s, partial);
    }
    for (int i = t; i < cnt; i += 256)
        atomicAdd(&lcnt[packed[pbase + i] >> SRCBITS], 1);
    // src-degree histogram from byte bucket (uint4-packed reads)
    {
        const uint* w = (const uint*)(sbytes + pbase);  // cap mult of 1024 -> aligned
        int nw = scnt >> 2;
        for (int i = t; i < nw; i += 256) {
            uint v = w[i];
            atomicAdd(&hist[v & 255u], 1u);
            atomicAdd(&hist[(v >> 8) & 255u], 1u);
            atomicAdd(&hist[(v >> 16) & 255u], 1u);
            atomicAdd(&hist[v >> 24], 1u);
        }
        for (int i = (nw << 2) + t; i < scnt; i += 256)
            atomicAdd(&hist[sbytes[pbase + i]], 1u);
    }
    __syncthreads();
    int obase = obase_s;
    for (int off = 1; off < BSIZE; off <<= 1) {
        int v = (t >= off) ? lcnt[t - off] : 0;
        __syncthreads();
        lcnt[t] += v;
        __syncthreads();
    }
    {
        int incl = lcnt[t];
        int excl = (t == 0) ? 0 : lcnt[t - 1];
        int node = nbase + t;
        if (node < N) {
            row_ptr[node] = obase + excl;
            norm_dst[node] = rsqrtf((float)max(incl - excl, 1));
            norm_src[node] = rsqrtf((float)max((int)hist[t], 1));
        }
        lptr[t] = obase + excl;
    }
    __syncthreads();
    for (int i = t; i < cnt; i += 256) {
        int p = packed[pbase + i];
        int slot = atomicAdd(&lptr[p >> SRCBITS], 1);
        col[slot] = p & SRCMASK;
    }
    // ---- feature fp32 -> bf16, pre-scaled by norm_src (hist is local) ----
    {
        const float4* f4 = (const float4*)feat;
        for (int e = t; e < BSIZE * 32; e += 256) {
            int row = e >> 5;
            int node = nbase + row;
            if (node < N) {
                float ns = rsqrtf((float)max((int)hist[row], 1));
                float4 v = f4[(size_t)node * 32 + (e & 31)];
                ushort4 o;
                o.x = f2bf(v.x * ns); o.y = f2bf(v.y * ns);
                o.z = f2bf(v.z * ns); o.w = f2bf(v.w * ns);
                ((ushort4*)feat_bf)[(size_t)node * 32 + (e & 31)] = o;
            }
        }
    }
}

// ---------- FUSED: r7 structure verbatim (proven 84us, occ 72%) ------------
// Block = 16 nodes x 4 waves; wave gathers 4 nodes (pre-scaled rows = pure
// row-sum, 4 loads in flight), barrier, each wave MFMAs 2 col-tiles (WT from
// L2, split across waves), bf16: LDS-union coalesced epilogue pre-scaled by
// norm_src; f32: direct stores (full-tile coverage merges in L2).
template <bool BF16_OUT>
__global__ __launch_bounds__(256) void agg_gemm_kernel(
    const u16* __restrict__ hs, const int* __restrict__ row_ptr,
    const int* __restrict__ col, const float* __restrict__ norm_src,
    const float* __restrict__ norm_dst, const u16* __restrict__ WT,
    const float* __restrict__ bias, float* __restrict__ out_f,
    u16* __restrict__ out_b, int N)
{
    __shared__ __align__(16) char smem[16 * 132 * 4];   // 8448B union
    u16   (*rows)[140] = (u16 (*)[140])smem;            // live in gather+MFMA
    float (*outt)[132] = (float (*)[132])smem;          // live in bf16 epilogue
    int wave = threadIdx.x >> 6;
    int lane = threadIdx.x & 63;
    int g    = lane >> 4;     // edge-group 0..3 (gather); quad (MFMA)
    int l16  = lane & 15;     // row position (gather); m16 (MFMA)
    int nbase = blockIdx.x * 16;
    const uint4* h4 = (const uint4*)hs;

    // ---- gather phase: each wave sums 4 nodes' pre-scaled rows ------------
    #pragma unroll
    for (int j = 0; j < 4; ++j) {
        int n = nbase + wave * 4 + j;
        float acc[8];
        #pragma unroll
        for (int k = 0; k < 8; ++k) acc[k] = 0.f;

        if (n < N) {
            int beg = row_ptr[n], end = row_ptr[n + 1];
            int i = beg + g;
            for (; i + 12 < end; i += 16) {       // 4 rows in flight
                int s0 = col[i], s1 = col[i + 4], s2 = col[i + 8], s3 = col[i + 12];
                uint4 v0 = h4[(size_t)s0 * 16 + l16];
                uint4 v1 = h4[(size_t)s1 * 16 + l16];
                uint4 v2 = h4[(size_t)s2 * 16 + l16];
                uint4 v3 = h4[(size_t)s3 * 16 + l16];
                add8(acc, v0); add8(acc, v1); add8(acc, v2); add8(acc, v3);
            }
            for (; i + 4 < end; i += 8) {         // 2 rows in flight
                int s0 = col[i], s1 = col[i + 4];
                uint4 v0 = h4[(size_t)s0 * 16 + l16];
                uint4 v1 = h4[(size_t)s1 * 16 + l16];
                add8(acc, v0); add8(acc, v1);
            }
            if (i < end) {
                int s = col[i];
                uint4 v = h4[(size_t)s * 16 + l16];
                add8(acc, v);
            }
        }

        #pragma unroll
        for (int k = 0; k < 8; ++k) {
            acc[k] += __shfl_xor(acc[k], 16, 64);
            acc[k] += __shfl_xor(acc[k], 32, 64);
        }

        if (g == 0) {
            float nd = (n < N) ? norm_dst[n] : 0.f;
            ushort4 lo, hi;
            lo.x = f2bf(acc[0] * nd); lo.y = f2bf(acc[1] * nd);
            lo.z = f2bf(acc[2] * nd); lo.w = f2bf(acc[3] * nd);
            hi.x = f2bf(acc[4] * nd); hi.y = f2bf(acc[5] * nd);
            hi.z = f2bf(acc[6] * nd); hi.w = f2bf(acc[7] * nd);
            ushort4* o = (ushort4*)&rows[wave * 4 + j][l16 * 8];
            o[0] = lo; o[1] = hi;
        }
    }
    __syncthreads();

    // ---- MFMA phase: wave handles col-tiles c0,c1 (W from global/L2) ------
    int m16 = l16, quad = g;
    int c0 = wave * 2, c1 = wave * 2 + 1;
    floatx4 accm0 = (floatx4){0.f, 0.f, 0.f, 0.f};
    floatx4 accm1 = (floatx4){0.f, 0.f, 0.f, 0.f};
    #pragma unroll
    for (int q = 0; q < 4; ++q) {
        short8 a = *(const short8*)&rows[m16][q * 32 + quad * 8];
        short8 b0 = *(const short8*)(WT + (size_t)(c0 * 16 + m16) * D + q * 32 + quad * 8);
        short8 b1 = *(const short8*)(WT + (size_t)(c1 * 16 + m16) * D + q * 32 + quad * 8);
        accm0 = __builtin_amdgcn_mfma_f32_16x16x32_bf16(a, b0, accm0, 0, 0, 0);
        accm1 = __builtin_amdgcn_mfma_f32_16x16x32_bf16(a, b1, accm1, 0, 0, 0);
    }
    float bv0 = bias[c0 * 16 + m16];
    float bv1 = bias[c1 * 16 + m16];

    if (BF16_OUT) {
        __syncthreads();   // all rows-reads done; safe to overwrite union
        #pragma unroll
        for (int r = 0; r < 4; ++r) {
            outt[quad * 4 + r][c0 * 16 + m16] = fmaxf(accm0[r] + bv0, 0.f);
            outt[quad * 4 + r][c1 * 16 + m16] = fmaxf(accm1[r] + bv1, 0.f);
        }
        __syncthreads();
        // coalesced 4KB burst; pre-scale by norm_src for next layer's gather
        int t = threadIdx.x;
        int r = t >> 4, c = (t & 15) * 8;
        if (nbase + r < N) {
            float ns = norm_src[nbase + r];
            ushort4 o0, o1;
            o0.x = f2bf(outt[r][c + 0] * ns); o0.y = f2bf(outt[r][c + 1] * ns);
            o0.z = f2bf(outt[r][c + 2] * ns); o0.w = f2bf(outt[r][c + 3] * ns);
            o1.x = f2bf(outt[r][c + 4] * ns); o1.y = f2bf(outt[r][c + 5] * ns);
            o1.z = f2bf(outt[r][c + 6] * ns); o1.w = f2bf(outt[r][c + 7] * ns);
            ushort4* o = (ushort4*)(out_b + (size_t)(nbase + r) * D + c);
            o[0] = o0; o[1] = o1;
        }
    } else {
        // direct stores: full 16x128 f32 tile covered per block -> L2 merges
        #pragma unroll
        for (int r = 0; r < 4; ++r) {
            int row = nbase + quad * 4 + r;
            if (row < N) {
                out_f[(size_t)row * D + c0 * 16 + m16] = fmaxf(accm0[r] + bv0, 0.f);
                out_f[(size_t)row * D + c1 * 16 + m16] = fmaxf(accm1[r] + bv1, 0.f);
            }
        }
    }
}

extern "C" void kernel_launch(void* const* d_in, const int* in_sizes, int n_in,
                              void* d_out, int out_size, void* d_ws, size_t ws_size,
                              hipStream_t stream)
{
    const float* features = (const float*)d_in[0];
    const int*   src      = (const int*)d_in[1];
    const int*   dst      = (const int*)d_in[2];
    const float* W1       = (const float*)d_in[3];
    const float* b1       = (const float*)d_in[4];
    const float* W2       = (const float*)d_in[5];
    const float* b2       = (const float*)d_in[6];
    float*       out      = (float*)d_out;

    const int N = in_sizes[0] / D;
    const int E = in_sizes[1];
    const int NB = (N + BSIZE - 1) >> BSHIFT;

    // padded bucket capacity: 2x mean, multiple of 1024;
    // bounded so packed(4B) + sbytes(1B) fit the N*D bf16 region (5B/slot).
    int cap = ((2 * (E / NB) + 2047) / 1024) * 1024;
    int cap_max = (int)(((size_t)N * D * 2 / (5 * NB)) / 1024 * 1024);
    if (cap > cap_max) cap = cap_max;

    // workspace layout
    u16*   scratch  = (u16*)d_ws;                   // N*D bf16 region (packed+sbytes)
    int*   packed   = (int*)scratch;                // NB*cap ints
    u8*    sbytes   = (u8*)(packed + (size_t)NB * cap);  // NB*cap bytes
    u16*   feat_bf  = scratch + (size_t)N * D;      // N*D bf16
    u16*   hs_bf    = feat_bf + (size_t)N * D;      // N*D bf16
    u16*   wT1      = hs_bf + (size_t)N * D;        // 16384 bf16
    u16*   wT2      = wT1 + D * D;                  // 16384 bf16
    float* norm_src = (float*)(wT2 + D * D);        // N
    float* norm_dst = norm_src + N;                 // N
    int*   iws          = (int*)(norm_dst + N);
    int*   row_ptr      = iws;                      // N+1
    int*   col          = row_ptr + N + 1;          // E
    int*   cursor_d     = col + E;                  // NBMAX
    int*   cursor_s     = cursor_d + NBMAX;         // NBMAX

    const int ebk = (E + CHUNK - 1) / CHUNK;
    const int fuse_blocks = (N + 15) / 16;

    // ---- CSR build: 3 launches before the fused layers ----
    setup_kernel<<<129, 256, 0, stream>>>(W1, W2, wT1, wT2, cursor_d, cursor_s,
                                          row_ptr, NB, N, E, cap);
    scatter_direct_kernel<<<ebk, 256, 0, stream>>>(src, dst, cursor_d, cursor_s, packed, sbytes, E, cap);
    fine_place_kernel<<<NB, 256, 0, stream>>>(
        packed, sbytes, cursor_d, cursor_s, row_ptr,
        norm_dst, norm_src, col, features, feat_bf, NB, N, cap);

    // ---- layer 1 (fused aggregate+GEMM, bf16 out pre-scaled by norm_src) ----
    agg_gemm_kernel<true><<<fuse_blocks, 256, 0, stream>>>(
        feat_bf, row_ptr, col, norm_src, norm_dst, wT1, b1, nullptr, hs_bf, N);

    // ---- layer 2 (fused aggregate+GEMM, f32 out) ----
    agg_gemm_kernel<false><<<fuse_blocks, 256, 0, stream>>>(
        hs_bf, row_ptr, col, norm_src, norm_dst, wT2, b2, out, nullptr, N);
}

// Round 11
// 359.633 us; speedup vs baseline: 1.3007x; 1.0019x over previous
//
#include <hip/hip_runtime.h>

#define D 128
#define BSHIFT 8
#define BSIZE 256        // nodes per fine bucket
#define NBMAX 512        // max buckets (N <= 131072)
#define CHUNK 4096       // edges per block in scatter
#define SRCBITS 17
#define SRCMASK 0x1FFFF

typedef unsigned int uint;
typedef unsigned short u16;
typedef unsigned char u8;
typedef __attribute__((ext_vector_type(8))) short short8;
typedef __attribute__((ext_vector_type(4))) float floatx4;

// ---- bf16 helpers (RNE) ----
__device__ __forceinline__ u16 f2bf(float f) {
    union { float f; uint u; } c; c.f = f;
    uint u = c.u;
    u += 0x7FFFu + ((u >> 16) & 1u);
    return (u16)(u >> 16);
}
__device__ __forceinline__ float bflo(uint u) {
    union { uint u; float f; } c; c.u = u << 16; return c.f;
}
__device__ __forceinline__ float bfhi(uint u) {
    union { uint u; float f; } c; c.u = u & 0xFFFF0000u; return c.f;
}
__device__ __forceinline__ void add8(float* acc, uint4 v) {
    acc[0] += bflo(v.x); acc[1] += bfhi(v.x);
    acc[2] += bflo(v.y); acc[3] += bfhi(v.y);
    acc[4] += bflo(v.z); acc[5] += bfhi(v.z);
    acc[6] += bflo(v.w); acc[7] += bfhi(v.w);
}

// ------- setup: W1/W2 transpose+convert, cursor init (one launch) ----------
__global__ __launch_bounds__(256) void setup_kernel(
    const float* __restrict__ W1, const float* __restrict__ W2,
    u16* __restrict__ wT1, u16* __restrict__ wT2,
    int* __restrict__ cursor_d, int* __restrict__ cursor_s, int NB, int cap)
{
    int b = blockIdx.x, t = threadIdx.x;
    if (b < 64) {
        int i = b * 256 + t;                 // i = k*128 + n
        int k = i >> 7, n = i & 127;
        wT1[n * 128 + k] = f2bf(W1[i]);
    } else if (b < 128) {
        int i = (b - 64) * 256 + t;
        int k = i >> 7, n = i & 127;
        wT2[n * 128 + k] = f2bf(W2[i]);
    } else {
        for (int j = t; j < NB; j += 256) {
            cursor_d[j] = j * cap;
            cursor_s[j] = j * cap;
        }
    }
}

// ------- single edge pass, NO per-edge global atomics (r5/r7 proven) -------
__global__ __launch_bounds__(256) void scatter_direct_kernel(
    const int* __restrict__ src, const int* __restrict__ dst,
    int* __restrict__ cursor_d, int* __restrict__ cursor_s,
    int* __restrict__ packed, u8* __restrict__ sbytes, int E, int cap)
{
    __shared__ int lcnt_d[NBMAX], lbase_d[NBMAX];
    __shared__ int lcnt_s[NBMAX], lbase_s[NBMAX];
    __shared__ int dbuf[CHUNK];      // 16 KB dst cache: read global once
    __shared__ int sbuf[CHUNK];      // 16 KB src cache: read global once
    int t = threadIdx.x;
    for (int j = t; j < NBMAX; j += 256) { lcnt_d[j] = 0; lcnt_s[j] = 0; }
    __syncthreads();
    int base = blockIdx.x * CHUNK;
    int end  = min(base + CHUNK, E);
    for (int i = base + t; i < end; i += 256) {
        int d = dst[i];
        int s = src[i];
        dbuf[i - base] = d;
        sbuf[i - base] = s;
        atomicAdd(&lcnt_d[d >> BSHIFT], 1);
        atomicAdd(&lcnt_s[s >> BSHIFT], 1);
    }
    __syncthreads();
    int rot = (blockIdx.x * 97) & (NBMAX - 1);
    for (int j = t; j < NBMAX; j += 256) {
        int jj = (j + rot) & (NBMAX - 1);
        int c = lcnt_d[jj];
        lbase_d[jj] = c ? atomicAdd(&cursor_d[jj], c) : 0;
        lcnt_d[jj] = 0;
        c = lcnt_s[jj];
        lbase_s[jj] = c ? atomicAdd(&cursor_s[jj], c) : 0;
        lcnt_s[jj] = 0;
    }
    __syncthreads();
    for (int i = base + t; i < end; i += 256) {
        int d = dbuf[i - base];
        int s = sbuf[i - base];
        int bd = d >> BSHIFT;
        int slot = lbase_d[bd] + atomicAdd(&lcnt_d[bd], 1);
        if (slot < (bd + 1) * cap)           // overflow guard (cap = 2x mean)
            packed[slot] = ((d & (BSIZE - 1)) << SRCBITS) | s;
        int bs = s >> BSHIFT;
        int slot2 = lbase_s[bs] + atomicAdd(&lcnt_s[bs], 1);
        if (slot2 < (bs + 1) * cap)
            sbytes[slot2] = (u8)(s & (BSIZE - 1));
    }
}

// ------- scan dst-bucket counts (one small block) --------------------------
__global__ __launch_bounds__(NBMAX) void bucket_scan_kernel(
    const int* __restrict__ cursor, int* __restrict__ bucket_ptr,
    int* __restrict__ row_ptr, int NB, int N, int E, int cap)
{
    __shared__ int sh[NBMAX];
    int t = threadIdx.x;
    int c = (t < NB) ? min(cursor[t] - t * cap, cap) : 0;
    sh[t] = c;
    __syncthreads();
    for (int off = 1; off < NBMAX; off <<= 1) {
        int v = (t >= off) ? sh[t - off] : 0;
        __syncthreads();
        sh[t] += v;
        __syncthreads();
    }
    if (t < NB) bucket_ptr[t] = sh[t] - c;   // exclusive prefix
    if (t == 0) row_ptr[N] = E;
}

// ------- fused per-bucket: fine CSR + src hist + PRE-SCALED feat convert ---
__global__ __launch_bounds__(256) void fine_place_kernel(
    const int* __restrict__ packed, const u8* __restrict__ sbytes,
    const int* __restrict__ cursor_d, const int* __restrict__ cursor_s,
    const int* __restrict__ bucket_ptr, int* __restrict__ row_ptr,
    float* __restrict__ norm_dst, float* __restrict__ norm_src,
    int* __restrict__ col,
    const float* __restrict__ feat, u16* __restrict__ feat_bf,
    int N, int cap)
{
    __shared__ int lcnt[BSIZE];
    __shared__ int lptr[BSIZE];
    __shared__ uint hist[BSIZE];
    int b = blockIdx.x, t = threadIdx.x;
    int nbase = b << BSHIFT;
    int pbase = b * cap;
    int cnt   = min(cursor_d[b] - pbase, cap);
    int scnt  = min(cursor_s[b] - pbase, cap);
    int obase = bucket_ptr[b];
    lcnt[t] = 0;
    hist[t] = 0;
    __syncthreads();
    for (int i = t; i < cnt; i += 256)
        atomicAdd(&lcnt[packed[pbase + i] >> SRCBITS], 1);
    // src-degree histogram from byte bucket (uint4-packed reads)
    {
        const uint* w = (const uint*)(sbytes + pbase);  // cap mult of 1024 -> aligned
        int nw = scnt >> 2;
        for (int i = t; i < nw; i += 256) {
            uint v = w[i];
            atomicAdd(&hist[v & 255u], 1u);
            atomicAdd(&hist[(v >> 8) & 255u], 1u);
            atomicAdd(&hist[(v >> 16) & 255u], 1u);
            atomicAdd(&hist[v >> 24], 1u);
        }
        for (int i = (nw << 2) + t; i < scnt; i += 256)
            atomicAdd(&hist[sbytes[pbase + i]], 1u);
    }
    __syncthreads();
    for (int off = 1; off < BSIZE; off <<= 1) {
        int v = (t >= off) ? lcnt[t - off] : 0;
        __syncthreads();
        lcnt[t] += v;
        __syncthreads();
    }
    {
        int incl = lcnt[t];
        int excl = (t == 0) ? 0 : lcnt[t - 1];
        int node = nbase + t;
        if (node < N) {
            row_ptr[node] = obase + excl;
            norm_dst[node] = rsqrtf((float)max(incl - excl, 1));
            norm_src[node] = rsqrtf((float)max((int)hist[t], 1));
        }
        lptr[t] = obase + excl;
    }
    __syncthreads();
    for (int i = t; i < cnt; i += 256) {
        int p = packed[pbase + i];
        int slot = atomicAdd(&lptr[p >> SRCBITS], 1);
        col[slot] = p & SRCMASK;
    }
    // ---- feature fp32 -> bf16, pre-scaled by norm_src (hist is local) ----
    {
        const float4* f4 = (const float4*)feat;
        for (int e = t; e < BSIZE * 32; e += 256) {
            int row = e >> 5;
            int node = nbase + row;
            if (node < N) {
                float ns = rsqrtf((float)max((int)hist[row], 1));
                float4 v = f4[(size_t)node * 32 + (e & 31)];
                ushort4 o;
                o.x = f2bf(v.x * ns); o.y = f2bf(v.y * ns);
                o.z = f2bf(v.z * ns); o.w = f2bf(v.w * ns);
                ((ushort4*)feat_bf)[(size_t)node * 32 + (e & 31)] = o;
            }
        }
    }
}

// ---------- SPLIT aggregate: r2's proven 62.8us geometry, pure row-sum -----
// One wave per dst node, 4 nodes/block, fully independent waves (no block
// coupling, no barriers). Inputs pre-scaled by norm_src -> no per-edge
// scalar loads; 4 row-loads in flight. Output row scaled by norm_dst.
__global__ __launch_bounds__(256) void aggregate_kernel(
    const u16* __restrict__ hs, const int* __restrict__ row_ptr,
    const int* __restrict__ col, const float* __restrict__ norm_dst,
    u16* __restrict__ agg, int N)
{
    int n = blockIdx.x * 4 + (threadIdx.x >> 6);
    if (n >= N) return;
    int lane = threadIdx.x & 63;
    int g    = lane >> 4;     // edge-group 0..3
    int l16  = lane & 15;     // position within row (8 bf16 elems)
    int beg = row_ptr[n], end = row_ptr[n + 1];
    const uint4* h4 = (const uint4*)hs;

    float acc[8];
    #pragma unroll
    for (int j = 0; j < 8; ++j) acc[j] = 0.f;

    int i = beg + g;
    for (; i + 12 < end; i += 16) {       // 4 rows in flight
        int s0 = col[i], s1 = col[i + 4], s2 = col[i + 8], s3 = col[i + 12];
        uint4 v0 = h4[(size_t)s0 * 16 + l16];
        uint4 v1 = h4[(size_t)s1 * 16 + l16];
        uint4 v2 = h4[(size_t)s2 * 16 + l16];
        uint4 v3 = h4[(size_t)s3 * 16 + l16];
        add8(acc, v0); add8(acc, v1); add8(acc, v2); add8(acc, v3);
    }
    for (; i + 4 < end; i += 8) {         // 2 rows in flight
        int s0 = col[i], s1 = col[i + 4];
        uint4 v0 = h4[(size_t)s0 * 16 + l16];
        uint4 v1 = h4[(size_t)s1 * 16 + l16];
        add8(acc, v0); add8(acc, v1);
    }
    if (i < end) {
        int s = col[i];
        uint4 v = h4[(size_t)s * 16 + l16];
        add8(acc, v);
    }

    #pragma unroll
    for (int j = 0; j < 8; ++j) {
        acc[j] += __shfl_xor(acc[j], 16, 64);
        acc[j] += __shfl_xor(acc[j], 32, 64);
    }

    if (g == 0) {
        float nd = norm_dst[n];
        ushort4 lo, hi;
        lo.x = f2bf(acc[0] * nd); lo.y = f2bf(acc[1] * nd);
        lo.z = f2bf(acc[2] * nd); lo.w = f2bf(acc[3] * nd);
        hi.x = f2bf(acc[4] * nd); hi.y = f2bf(acc[5] * nd);
        hi.z = f2bf(acc[6] * nd); hi.w = f2bf(acc[7] * nd);
        ushort4* o = (ushort4*)(agg + (size_t)n * D + l16 * 8);
        o[0] = lo; o[1] = hi;
    }
}

// ---------- SPLIT GEMM: out = relu(A @ W + b) (r0-proven structure) --------
// 128 rows/block, 4 waves x 32 rows, 8 col-tiles each. A is L3-resident
// (just written by aggregate). bf16 out: wave-private LDS staging (no
// barrier) -> coalesced 16B/lane stores, pre-scaled by norm_src for the
// next layer. f32 out: direct stores (full-tile coverage merges, proven).
template <bool BF16_OUT>
__global__ __launch_bounds__(256) void gemm_mfma_kernel(
    const u16* __restrict__ A, const u16* __restrict__ WT,
    const float* __restrict__ bias, const float* __restrict__ norm_src,
    float* __restrict__ out_f, u16* __restrict__ out_b, int N)
{
    int wave = threadIdx.x >> 6;
    int lane = threadIdx.x & 63;
    int m16  = lane & 15;
    int quad = lane >> 4;
    int row_base = blockIdx.x * 128 + wave * 32;

    int rA0 = min(row_base + m16, N - 1);
    int rA1 = min(row_base + 16 + m16, N - 1);
    const short8* Arow0 = (const short8*)(A + (size_t)rA0 * D);
    const short8* Arow1 = (const short8*)(A + (size_t)rA1 * D);

    floatx4 acc0[8], acc1[8];
    #pragma unroll
    for (int c = 0; c < 8; ++c) {
        acc0[c] = (floatx4){0.f, 0.f, 0.f, 0.f};
        acc1[c] = (floatx4){0.f, 0.f, 0.f, 0.f};
    }

    #pragma unroll
    for (int q = 0; q < 4; ++q) {
        short8 a0 = Arow0[q * 4 + quad];
        short8 a1 = Arow1[q * 4 + quad];
        #pragma unroll
        for (int c = 0; c < 8; ++c) {
            short8 b = *(const short8*)(WT + (size_t)(c * 16 + m16) * D + q * 32 + quad * 8);
            acc0[c] = __builtin_amdgcn_mfma_f32_16x16x32_bf16(a0, b, acc0[c], 0, 0, 0);
            acc1[c] = __builtin_amdgcn_mfma_f32_16x16x32_bf16(a1, b, acc1[c], 0, 0, 0);
        }
    }

    if constexpr (BF16_OUT) {
        __shared__ u16 ob[4][32][136];
        u16 (*ow)[136] = ob[wave];
        float ns0[4], ns1[4];
        #pragma unroll
        for (int r = 0; r < 4; ++r) {
            int row0 = row_base + quad * 4 + r;
            int row1 = row0 + 16;
            ns0[r] = (row0 < N) ? norm_src[row0] : 0.f;
            ns1[r] = (row1 < N) ? norm_src[row1] : 0.f;
        }
        #pragma unroll
        for (int c = 0; c < 8; ++c) {
            float bv = bias[c * 16 + m16];
            #pragma unroll
            for (int r = 0; r < 4; ++r) {
                ow[quad * 4 + r][c * 16 + m16]      = f2bf(fmaxf(acc0[c][r] + bv, 0.f) * ns0[r]);
                ow[quad * 4 + r + 16][c * 16 + m16] = f2bf(fmaxf(acc1[c][r] + bv, 0.f) * ns1[r]);
            }
        }
        // wave-local LDS (no barrier); coalesced stores: 16B/lane, 4 rows/pass
        #pragma unroll
        for (int p = 0; p < 8; ++p) {
            int rl = p * 4 + quad;
            int row = row_base + rl;
            if (row < N) {
                ushort4 a0 = *(const ushort4*)&ow[rl][m16 * 8];
                ushort4 a1 = *(const ushort4*)&ow[rl][m16 * 8 + 4];
                ushort4* o = (ushort4*)(out_b + (size_t)row * D + m16 * 8);
                o[0] = a0; o[1] = a1;
            }
        }
    } else {
        // direct stores: block covers full 128x128 f32 tile -> L2 merges
        #pragma unroll
        for (int c = 0; c < 8; ++c) {
            float bv = bias[c * 16 + m16];
            #pragma unroll
            for (int r = 0; r < 4; ++r) {
                int row0 = row_base + quad * 4 + r;
                int row1 = row0 + 16;
                if (row0 < N)
                    out_f[(size_t)row0 * D + c * 16 + m16] = fmaxf(acc0[c][r] + bv, 0.f);
                if (row1 < N)
                    out_f[(size_t)row1 * D + c * 16 + m16] = fmaxf(acc1[c][r] + bv, 0.f);
            }
        }
    }
}

extern "C" void kernel_launch(void* const* d_in, const int* in_sizes, int n_in,
                              void* d_out, int out_size, void* d_ws, size_t ws_size,
                              hipStream_t stream)
{
    const float* features = (const float*)d_in[0];
    const int*   src      = (const int*)d_in[1];
    const int*   dst      = (const int*)d_in[2];
    const float* W1       = (const float*)d_in[3];
    const float* b1       = (const float*)d_in[4];
    const float* W2       = (const float*)d_in[5];
    const float* b2       = (const float*)d_in[6];
    float*       out      = (float*)d_out;

    const int N = in_sizes[0] / D;
    const int E = in_sizes[1];
    const int NB = (N + BSIZE - 1) >> BSHIFT;

    // padded bucket capacity: 2x mean, multiple of 1024;
    // bounded so packed(4B) + sbytes(1B) fit the N*D bf16 region (5B/slot).
    int cap = ((2 * (E / NB) + 2047) / 1024) * 1024;
    int cap_max = (int)(((size_t)N * D * 2 / (5 * NB)) / 1024 * 1024);
    if (cap > cap_max) cap = cap_max;

    // workspace layout
    u16*   scratch  = (u16*)d_ws;                   // N*D bf16 region
    int*   packed   = (int*)scratch;                // NB*cap ints (dead after fine_place)
    u8*    sbytes   = (u8*)(packed + (size_t)NB * cap);  // NB*cap bytes
    u16*   agg_bf   = scratch;                      // reuse after fine_place
    u16*   feat_bf  = scratch + (size_t)N * D;      // N*D bf16
    u16*   hs_bf    = feat_bf + (size_t)N * D;      // N*D bf16
    u16*   wT1      = hs_bf + (size_t)N * D;        // 16384 bf16
    u16*   wT2      = wT1 + D * D;                  // 16384 bf16
    float* norm_src = (float*)(wT2 + D * D);        // N
    float* norm_dst = norm_src + N;                 // N
    int*   iws          = (int*)(norm_dst + N);
    int*   row_ptr      = iws;                      // N+1
    int*   col          = row_ptr + N + 1;          // E
    int*   bucket_ptr   = col + E;                  // NBMAX+1
    int*   cursor_d     = bucket_ptr + NBMAX + 1;   // NBMAX
    int*   cursor_s     = cursor_d + NBMAX;         // NBMAX

    const int ebk = (E + CHUNK - 1) / CHUNK;
    const int agg_blocks  = (N + 3) / 4;
    const int gemm_blocks = (N + 127) / 128;

    // ---- CSR build (r5/r7-proven path) ----
    setup_kernel<<<129, 256, 0, stream>>>(W1, W2, wT1, wT2, cursor_d, cursor_s, NB, cap);
    scatter_direct_kernel<<<ebk, 256, 0, stream>>>(src, dst, cursor_d, cursor_s, packed, sbytes, E, cap);
    bucket_scan_kernel<<<1, NBMAX, 0, stream>>>(cursor_d, bucket_ptr, row_ptr, NB, N, E, cap);
    fine_place_kernel<<<NB, 256, 0, stream>>>(
        packed, sbytes, cursor_d, cursor_s, bucket_ptr, row_ptr,
        norm_dst, norm_src, col, features, feat_bf, N, cap);

    // ---- layer 1: split aggregate + GEMM (bf16 out, pre-scaled by ns) ----
    aggregate_kernel<<<agg_blocks, 256, 0, stream>>>(
        feat_bf, row_ptr, col, norm_dst, agg_bf, N);
    gemm_mfma_kernel<true><<<gemm_blocks, 256, 0, stream>>>(
        agg_bf, wT1, b1, norm_src, nullptr, hs_bf, N);

    // ---- layer 2: split aggregate + GEMM (f32 out) ----
    aggregate_kernel<<<agg_blocks, 256, 0, stream>>>(
        hs_bf, row_ptr, col, norm_dst, agg_bf, N);
    gemm_mfma_kernel<false><<<gemm_blocks, 256, 0, stream>>>(
        agg_bf, wT2, b2, nullptr, out, nullptr, N);
}

// Round 12
// 343.188 us; speedup vs baseline: 1.3630x; 1.0479x over previous
//
#include <hip/hip_runtime.h>

#define D 128
#define BSHIFT 8
#define BSIZE 256        // nodes per fine bucket
#define NBMAX 512        // max buckets (N <= 131072)
#define CHUNK 4096       // edges per block in scatter
#define SRCBITS 17
#define SRCMASK 0x1FFFF

typedef unsigned int uint;
typedef unsigned short u16;
typedef unsigned char u8;
typedef __attribute__((ext_vector_type(8))) short short8;
typedef __attribute__((ext_vector_type(4))) float floatx4;

// ---- bf16 helpers (RNE) ----
__device__ __forceinline__ u16 f2bf(float f) {
    union { float f; uint u; } c; c.f = f;
    uint u = c.u;
    u += 0x7FFFu + ((u >> 16) & 1u);
    return (u16)(u >> 16);
}
__device__ __forceinline__ float bflo(uint u) {
    union { uint u; float f; } c; c.u = u << 16; return c.f;
}
__device__ __forceinline__ float bfhi(uint u) {
    union { uint u; float f; } c; c.u = u & 0xFFFF0000u; return c.f;
}
__device__ __forceinline__ void add8(float* acc, uint4 v) {
    acc[0] += bflo(v.x); acc[1] += bfhi(v.x);
    acc[2] += bflo(v.y); acc[3] += bfhi(v.y);
    acc[4] += bflo(v.z); acc[5] += bfhi(v.z);
    acc[6] += bflo(v.w); acc[7] += bfhi(v.w);
}

// ------- setup: W1/W2 transpose+convert, cursor init (one launch) ----------
__global__ __launch_bounds__(256) void setup_kernel(
    const float* __restrict__ W1, const float* __restrict__ W2,
    u16* __restrict__ wT1, u16* __restrict__ wT2,
    int* __restrict__ cursor_d, int* __restrict__ cursor_s, int NB, int cap)
{
    int b = blockIdx.x, t = threadIdx.x;
    if (b < 64) {
        int i = b * 256 + t;                 // i = k*128 + n
        int k = i >> 7, n = i & 127;
        wT1[n * 128 + k] = f2bf(W1[i]);
    } else if (b < 128) {
        int i = (b - 64) * 256 + t;
        int k = i >> 7, n = i & 127;
        wT2[n * 128 + k] = f2bf(W2[i]);
    } else {
        for (int j = t; j < NB; j += 256) {
            cursor_d[j] = j * cap;
            cursor_s[j] = j * cap;
        }
    }
}

// ------- single edge pass, NO per-edge global atomics (r5/r7 proven) -------
__global__ __launch_bounds__(256) void scatter_direct_kernel(
    const int* __restrict__ src, const int* __restrict__ dst,
    int* __restrict__ cursor_d, int* __restrict__ cursor_s,
    int* __restrict__ packed, u8* __restrict__ sbytes, int E, int cap)
{
    __shared__ int lcnt_d[NBMAX], lbase_d[NBMAX];
    __shared__ int lcnt_s[NBMAX], lbase_s[NBMAX];
    __shared__ int dbuf[CHUNK];      // 16 KB dst cache: read global once
    __shared__ int sbuf[CHUNK];      // 16 KB src cache: read global once
    int t = threadIdx.x;
    for (int j = t; j < NBMAX; j += 256) { lcnt_d[j] = 0; lcnt_s[j] = 0; }
    __syncthreads();
    int base = blockIdx.x * CHUNK;
    int end  = min(base + CHUNK, E);
    for (int i = base + t; i < end; i += 256) {
        int d = dst[i];
        int s = src[i];
        dbuf[i - base] = d;
        sbuf[i - base] = s;
        atomicAdd(&lcnt_d[d >> BSHIFT], 1);
        atomicAdd(&lcnt_s[s >> BSHIFT], 1);
    }
    __syncthreads();
    int rot = (blockIdx.x * 97) & (NBMAX - 1);
    for (int j = t; j < NBMAX; j += 256) {
        int jj = (j + rot) & (NBMAX - 1);
        int c = lcnt_d[jj];
        lbase_d[jj] = c ? atomicAdd(&cursor_d[jj], c) : 0;
        lcnt_d[jj] = 0;
        c = lcnt_s[jj];
        lbase_s[jj] = c ? atomicAdd(&cursor_s[jj], c) : 0;
        lcnt_s[jj] = 0;
    }
    __syncthreads();
    for (int i = base + t; i < end; i += 256) {
        int d = dbuf[i - base];
        int s = sbuf[i - base];
        int bd = d >> BSHIFT;
        int slot = lbase_d[bd] + atomicAdd(&lcnt_d[bd], 1);
        if (slot < (bd + 1) * cap)           // overflow guard (cap = 2x mean)
            packed[slot] = ((d & (BSIZE - 1)) << SRCBITS) | s;
        int bs = s >> BSHIFT;
        int slot2 = lbase_s[bs] + atomicAdd(&lcnt_s[bs], 1);
        if (slot2 < (bs + 1) * cap)
            sbytes[slot2] = (u8)(s & (BSIZE - 1));
    }
}

// ------- scan dst-bucket counts (one small block) --------------------------
__global__ __launch_bounds__(NBMAX) void bucket_scan_kernel(
    const int* __restrict__ cursor, int* __restrict__ bucket_ptr,
    int* __restrict__ row_ptr, int NB, int N, int E, int cap)
{
    __shared__ int sh[NBMAX];
    int t = threadIdx.x;
    int c = (t < NB) ? min(cursor[t] - t * cap, cap) : 0;
    sh[t] = c;
    __syncthreads();
    for (int off = 1; off < NBMAX; off <<= 1) {
        int v = (t >= off) ? sh[t - off] : 0;
        __syncthreads();
        sh[t] += v;
        __syncthreads();
    }
    if (t < NB) bucket_ptr[t] = sh[t] - c;   // exclusive prefix
    if (t == 0) row_ptr[N] = E;
}

// ------- fused per-bucket: fine CSR + src hist + PRE-SCALED feat convert ---
__global__ __launch_bounds__(256) void fine_place_kernel(
    const int* __restrict__ packed, const u8* __restrict__ sbytes,
    const int* __restrict__ cursor_d, const int* __restrict__ cursor_s,
    const int* __restrict__ bucket_ptr, int* __restrict__ row_ptr,
    float* __restrict__ norm_dst, float* __restrict__ norm_src,
    int* __restrict__ col,
    const float* __restrict__ feat, u16* __restrict__ feat_bf,
    int N, int cap)
{
    __shared__ int lcnt[BSIZE];
    __shared__ int lptr[BSIZE];
    __shared__ uint hist[BSIZE];
    int b = blockIdx.x, t = threadIdx.x;
    int nbase = b << BSHIFT;
    int pbase = b * cap;
    int cnt   = min(cursor_d[b] - pbase, cap);
    int scnt  = min(cursor_s[b] - pbase, cap);
    int obase = bucket_ptr[b];
    lcnt[t] = 0;
    hist[t] = 0;
    __syncthreads();
    for (int i = t; i < cnt; i += 256)
        atomicAdd(&lcnt[packed[pbase + i] >> SRCBITS], 1);
    // src-degree histogram from byte bucket (uint4-packed reads)
    {
        const uint* w = (const uint*)(sbytes + pbase);  // cap mult of 1024 -> aligned
        int nw = scnt >> 2;
        for (int i = t; i < nw; i += 256) {
            uint v = w[i];
            atomicAdd(&hist[v & 255u], 1u);
            atomicAdd(&hist[(v >> 8) & 255u], 1u);
            atomicAdd(&hist[(v >> 16) & 255u], 1u);
            atomicAdd(&hist[v >> 24], 1u);
        }
        for (int i = (nw << 2) + t; i < scnt; i += 256)
            atomicAdd(&hist[sbytes[pbase + i]], 1u);
    }
    __syncthreads();
    for (int off = 1; off < BSIZE; off <<= 1) {
        int v = (t >= off) ? lcnt[t - off] : 0;
        __syncthreads();
        lcnt[t] += v;
        __syncthreads();
    }
    {
        int incl = lcnt[t];
        int excl = (t == 0) ? 0 : lcnt[t - 1];
        int node = nbase + t;
        if (node < N) {
            row_ptr[node] = obase + excl;
            norm_dst[node] = rsqrtf((float)max(incl - excl, 1));
            norm_src[node] = rsqrtf((float)max((int)hist[t], 1));
        }
        lptr[t] = obase + excl;
    }
    __syncthreads();
    for (int i = t; i < cnt; i += 256) {
        int p = packed[pbase + i];
        int slot = atomicAdd(&lptr[p >> SRCBITS], 1);
        col[slot] = p & SRCMASK;
    }
    // ---- feature fp32 -> bf16, pre-scaled by norm_src (hist is local) ----
    {
        const float4* f4 = (const float4*)feat;
        for (int e = t; e < BSIZE * 32; e += 256) {
            int row = e >> 5;
            int node = nbase + row;
            if (node < N) {
                float ns = rsqrtf((float)max((int)hist[row], 1));
                float4 v = f4[(size_t)node * 32 + (e & 31)];
                ushort4 o;
                o.x = f2bf(v.x * ns); o.y = f2bf(v.y * ns);
                o.z = f2bf(v.z * ns); o.w = f2bf(v.w * ns);
                ((ushort4*)feat_bf)[(size_t)node * 32 + (e & 31)] = o;
            }
        }
    }
}

// ---------- FUSED r7 + DYNAMIC NODE QUEUE ----------------------------------
// Block = 16 nodes x 4 waves. Waves grab node indices from an LDS counter
// (greedy list scheduling: block gather makespan ~ sum/4 + one job, vs
// static max-of-4-sums) - same arithmetic per node, bitwise-identical out.
// bf16 epilogue: separate outt LDS (12.9KB total still 8 blocks/CU) - one
// fewer barrier than the r7 union. f32: direct stores (merge proven).
template <bool BF16_OUT>
__global__ __launch_bounds__(256) void agg_gemm_kernel(
    const u16* __restrict__ hs, const int* __restrict__ row_ptr,
    const int* __restrict__ col, const float* __restrict__ norm_src,
    const float* __restrict__ norm_dst, const u16* __restrict__ WT,
    const float* __restrict__ bias, float* __restrict__ out_f,
    u16* __restrict__ out_b, int N)
{
    __shared__ u16 rows[16][140];    // 4.5KB: conflict-low A-frag reads
    __shared__ int qhead;
    int wave = threadIdx.x >> 6;
    int lane = threadIdx.x & 63;
    int g    = lane >> 4;     // edge-group 0..3 (gather); quad (MFMA)
    int l16  = lane & 15;     // row position (gather); m16 (MFMA)
    int nbase = blockIdx.x * 16;
    const uint4* h4 = (const uint4*)hs;
    if (threadIdx.x == 0) qhead = 0;
    __syncthreads();

    // ---- gather phase: dynamic node pull -----------------------------------
    for (;;) {
        int j = 0;
        if (lane == 0) j = atomicAdd(&qhead, 1);
        j = __shfl(j, 0, 64);
        if (j >= 16) break;
        int n = nbase + j;
        float acc[8];
        #pragma unroll
        for (int k = 0; k < 8; ++k) acc[k] = 0.f;

        if (n < N) {
            int beg = row_ptr[n], end = row_ptr[n + 1];
            int i = beg + g;
            for (; i + 12 < end; i += 16) {       // 4 rows in flight
                int s0 = col[i], s1 = col[i + 4], s2 = col[i + 8], s3 = col[i + 12];
                uint4 v0 = h4[(size_t)s0 * 16 + l16];
                uint4 v1 = h4[(size_t)s1 * 16 + l16];
                uint4 v2 = h4[(size_t)s2 * 16 + l16];
                uint4 v3 = h4[(size_t)s3 * 16 + l16];
                add8(acc, v0); add8(acc, v1); add8(acc, v2); add8(acc, v3);
            }
            for (; i + 4 < end; i += 8) {         // 2 rows in flight
                int s0 = col[i], s1 = col[i + 4];
                uint4 v0 = h4[(size_t)s0 * 16 + l16];
                uint4 v1 = h4[(size_t)s1 * 16 + l16];
                add8(acc, v0); add8(acc, v1);
            }
            if (i < end) {
                int s = col[i];
                uint4 v = h4[(size_t)s * 16 + l16];
                add8(acc, v);
            }
        }

        #pragma unroll
        for (int k = 0; k < 8; ++k) {
            acc[k] += __shfl_xor(acc[k], 16, 64);
            acc[k] += __shfl_xor(acc[k], 32, 64);
        }

        if (g == 0) {
            float nd = (n < N) ? norm_dst[n] : 0.f;
            ushort4 lo, hi;
            lo.x = f2bf(acc[0] * nd); lo.y = f2bf(acc[1] * nd);
            lo.z = f2bf(acc[2] * nd); lo.w = f2bf(acc[3] * nd);
            hi.x = f2bf(acc[4] * nd); hi.y = f2bf(acc[5] * nd);
            hi.z = f2bf(acc[6] * nd); hi.w = f2bf(acc[7] * nd);
            ushort4* o = (ushort4*)&rows[j][l16 * 8];
            o[0] = lo; o[1] = hi;
        }
    }
    __syncthreads();

    // ---- MFMA phase: wave handles col-tiles c0,c1 (W from global/L2) ------
    int m16 = l16, quad = g;
    int c0 = wave * 2, c1 = wave * 2 + 1;
    floatx4 accm0 = (floatx4){0.f, 0.f, 0.f, 0.f};
    floatx4 accm1 = (floatx4){0.f, 0.f, 0.f, 0.f};
    #pragma unroll
    for (int q = 0; q < 4; ++q) {
        short8 a = *(const short8*)&rows[m16][q * 32 + quad * 8];
        short8 b0 = *(const short8*)(WT + (size_t)(c0 * 16 + m16) * D + q * 32 + quad * 8);
        short8 b1 = *(const short8*)(WT + (size_t)(c1 * 16 + m16) * D + q * 32 + quad * 8);
        accm0 = __builtin_amdgcn_mfma_f32_16x16x32_bf16(a, b0, accm0, 0, 0, 0);
        accm1 = __builtin_amdgcn_mfma_f32_16x16x32_bf16(a, b1, accm1, 0, 0, 0);
    }
    float bv0 = bias[c0 * 16 + m16];
    float bv1 = bias[c1 * 16 + m16];

    if constexpr (BF16_OUT) {
        __shared__ float outt[16][132];   // separate tile: no union barrier
        #pragma unroll
        for (int r = 0; r < 4; ++r) {
            outt[quad * 4 + r][c0 * 16 + m16] = fmaxf(accm0[r] + bv0, 0.f);
            outt[quad * 4 + r][c1 * 16 + m16] = fmaxf(accm1[r] + bv1, 0.f);
        }
        __syncthreads();
        // coalesced 4KB burst; pre-scale by norm_src for next layer's gather
        int t = threadIdx.x;
        int r = t >> 4, c = (t & 15) * 8;
        if (nbase + r < N) {
            float ns = norm_src[nbase + r];
            ushort4 o0, o1;
            o0.x = f2bf(outt[r][c + 0] * ns); o0.y = f2bf(outt[r][c + 1] * ns);
            o0.z = f2bf(outt[r][c + 2] * ns); o0.w = f2bf(outt[r][c + 3] * ns);
            o1.x = f2bf(outt[r][c + 4] * ns); o1.y = f2bf(outt[r][c + 5] * ns);
            o1.z = f2bf(outt[r][c + 6] * ns); o1.w = f2bf(outt[r][c + 7] * ns);
            ushort4* o = (ushort4*)(out_b + (size_t)(nbase + r) * D + c);
            o[0] = o0; o[1] = o1;
        }
    } else {
        // direct stores: full 16x128 f32 tile covered per block -> L2 merges
        #pragma unroll
        for (int r = 0; r < 4; ++r) {
            int row = nbase + quad * 4 + r;
            if (row < N) {
                out_f[(size_t)row * D + c0 * 16 + m16] = fmaxf(accm0[r] + bv0, 0.f);
                out_f[(size_t)row * D + c1 * 16 + m16] = fmaxf(accm1[r] + bv1, 0.f);
            }
        }
    }
}

extern "C" void kernel_launch(void* const* d_in, const int* in_sizes, int n_in,
                              void* d_out, int out_size, void* d_ws, size_t ws_size,
                              hipStream_t stream)
{
    const float* features = (const float*)d_in[0];
    const int*   src      = (const int*)d_in[1];
    const int*   dst      = (const int*)d_in[2];
    const float* W1       = (const float*)d_in[3];
    const float* b1       = (const float*)d_in[4];
    const float* W2       = (const float*)d_in[5];
    const float* b2       = (const float*)d_in[6];
    float*       out      = (float*)d_out;

    const int N = in_sizes[0] / D;
    const int E = in_sizes[1];
    const int NB = (N + BSIZE - 1) >> BSHIFT;

    // padded bucket capacity: 2x mean, multiple of 1024;
    // bounded so packed(4B) + sbytes(1B) fit the N*D bf16 region (5B/slot).
    int cap = ((2 * (E / NB) + 2047) / 1024) * 1024;
    int cap_max = (int)(((size_t)N * D * 2 / (5 * NB)) / 1024 * 1024);
    if (cap > cap_max) cap = cap_max;

    // workspace layout
    u16*   scratch  = (u16*)d_ws;                   // N*D bf16 region (packed+sbytes)
    int*   packed   = (int*)scratch;                // NB*cap ints
    u8*    sbytes   = (u8*)(packed + (size_t)NB * cap);  // NB*cap bytes
    u16*   feat_bf  = scratch + (size_t)N * D;      // N*D bf16
    u16*   hs_bf    = feat_bf + (size_t)N * D;      // N*D bf16
    u16*   wT1      = hs_bf + (size_t)N * D;        // 16384 bf16
    u16*   wT2      = wT1 + D * D;                  // 16384 bf16
    float* norm_src = (float*)(wT2 + D * D);        // N
    float* norm_dst = norm_src + N;                 // N
    int*   iws          = (int*)(norm_dst + N);
    int*   row_ptr      = iws;                      // N+1
    int*   col          = row_ptr + N + 1;          // E
    int*   bucket_ptr   = col + E;                  // NBMAX+1
    int*   cursor_d     = bucket_ptr + NBMAX + 1;   // NBMAX
    int*   cursor_s     = cursor_d + NBMAX;         // NBMAX

    const int ebk = (E + CHUNK - 1) / CHUNK;
    const int fuse_blocks = (N + 15) / 16;

    // ---- CSR build (r5/r7-proven path) ----
    setup_kernel<<<129, 256, 0, stream>>>(W1, W2, wT1, wT2, cursor_d, cursor_s, NB, cap);
    scatter_direct_kernel<<<ebk, 256, 0, stream>>>(src, dst, cursor_d, cursor_s, packed, sbytes, E, cap);
    bucket_scan_kernel<<<1, NBMAX, 0, stream>>>(cursor_d, bucket_ptr, row_ptr, NB, N, E, cap);
    fine_place_kernel<<<NB, 256, 0, stream>>>(
        packed, sbytes, cursor_d, cursor_s, bucket_ptr, row_ptr,
        norm_dst, norm_src, col, features, feat_bf, N, cap);

    // ---- layer 1 (fused aggregate+GEMM, bf16 out pre-scaled by norm_src) ----
    agg_gemm_kernel<true><<<fuse_blocks, 256, 0, stream>>>(
        feat_bf, row_ptr, col, norm_src, norm_dst, wT1, b1, nullptr, hs_bf, N);

    // ---- layer 2 (fused aggregate+GEMM, f32 out) ----
    agg_gemm_kernel<false><<<fuse_blocks, 256, 0, stream>>>(
        hs_bf, row_ptr, col, norm_src, norm_dst, wT2, b2, out, nullptr, N);
}

// Round 13
// 340.102 us; speedup vs baseline: 1.3754x; 1.0091x over previous
//
#include <hip/hip_runtime.h>

#define D 128
#define BSHIFT 8
#define BSIZE 256        // nodes per fine bucket
#define NBMAX 512        // max buckets (N <= 131072)
#define CHUNK 4096       // edges per block in scatter
#define SRCBITS 17
#define SRCMASK 0x1FFFF

typedef unsigned int uint;
typedef unsigned short u16;
typedef unsigned char u8;
typedef __attribute__((ext_vector_type(8))) short short8;
typedef __attribute__((ext_vector_type(4))) float floatx4;

// ---- bf16 helpers (RNE) ----
__device__ __forceinline__ u16 f2bf(float f) {
    union { float f; uint u; } c; c.f = f;
    uint u = c.u;
    u += 0x7FFFu + ((u >> 16) & 1u);
    return (u16)(u >> 16);
}
__device__ __forceinline__ float bflo(uint u) {
    union { uint u; float f; } c; c.u = u << 16; return c.f;
}
__device__ __forceinline__ float bfhi(uint u) {
    union { uint u; float f; } c; c.u = u & 0xFFFF0000u; return c.f;
}
__device__ __forceinline__ void add8(float* acc, uint4 v) {
    acc[0] += bflo(v.x); acc[1] += bfhi(v.x);
    acc[2] += bflo(v.y); acc[3] += bfhi(v.y);
    acc[4] += bflo(v.z); acc[5] += bfhi(v.z);
    acc[6] += bflo(v.w); acc[7] += bfhi(v.w);
}

// ------- setup: W1/W2 transpose+convert, cursor init (one launch) ----------
__global__ __launch_bounds__(256) void setup_kernel(
    const float* __restrict__ W1, const float* __restrict__ W2,
    u16* __restrict__ wT1, u16* __restrict__ wT2,
    int* __restrict__ cursor_d, int* __restrict__ cursor_s, int NB, int cap)
{
    int b = blockIdx.x, t = threadIdx.x;
    if (b < 64) {
        int i = b * 256 + t;                 // i = k*128 + n
        int k = i >> 7, n = i & 127;
        wT1[n * 128 + k] = f2bf(W1[i]);
    } else if (b < 128) {
        int i = (b - 64) * 256 + t;
        int k = i >> 7, n = i & 127;
        wT2[n * 128 + k] = f2bf(W2[i]);
    } else {
        for (int j = t; j < NB; j += 256) {
            cursor_d[j] = j * cap;
            cursor_s[j] = j * cap;
        }
    }
}

// ------- single edge pass, NO per-edge global atomics ----------------------
__global__ __launch_bounds__(256) void scatter_direct_kernel(
    const int* __restrict__ src, const int* __restrict__ dst,
    int* __restrict__ cursor_d, int* __restrict__ cursor_s,
    int* __restrict__ packed, u8* __restrict__ sbytes, int E, int cap)
{
    __shared__ int lcnt_d[NBMAX], lbase_d[NBMAX];
    __shared__ int lcnt_s[NBMAX], lbase_s[NBMAX];
    __shared__ int dbuf[CHUNK];      // 16 KB dst cache: read global once
    __shared__ int sbuf[CHUNK];      // 16 KB src cache: read global once
    int t = threadIdx.x;
    for (int j = t; j < NBMAX; j += 256) { lcnt_d[j] = 0; lcnt_s[j] = 0; }
    __syncthreads();
    int base = blockIdx.x * CHUNK;
    int end  = min(base + CHUNK, E);
    for (int i = base + t; i < end; i += 256) {
        int d = dst[i];
        int s = src[i];
        dbuf[i - base] = d;
        sbuf[i - base] = s;
        atomicAdd(&lcnt_d[d >> BSHIFT], 1);
        atomicAdd(&lcnt_s[s >> BSHIFT], 1);
    }
    __syncthreads();
    int rot = (blockIdx.x * 97) & (NBMAX - 1);
    for (int j = t; j < NBMAX; j += 256) {
        int jj = (j + rot) & (NBMAX - 1);
        int c = lcnt_d[jj];
        lbase_d[jj] = c ? atomicAdd(&cursor_d[jj], c) : 0;
        lcnt_d[jj] = 0;
        c = lcnt_s[jj];
        lbase_s[jj] = c ? atomicAdd(&cursor_s[jj], c) : 0;
        lcnt_s[jj] = 0;
    }
    __syncthreads();
    for (int i = base + t; i < end; i += 256) {
        int d = dbuf[i - base];
        int s = sbuf[i - base];
        int bd = d >> BSHIFT;
        int slot = lbase_d[bd] + atomicAdd(&lcnt_d[bd], 1);
        if (slot < (bd + 1) * cap)           // overflow guard (cap = 2x mean)
            packed[slot] = ((d & (BSIZE - 1)) << SRCBITS) | s;
        int bs = s >> BSHIFT;
        int slot2 = lbase_s[bs] + atomicAdd(&lcnt_s[bs], 1);
        if (slot2 < (bs + 1) * cap)
            sbytes[slot2] = (u8)(s & (BSIZE - 1));
    }
}

// ------- scan dst-bucket counts (one small block) --------------------------
__global__ __launch_bounds__(NBMAX) void bucket_scan_kernel(
    const int* __restrict__ cursor, int* __restrict__ bucket_ptr,
    int* __restrict__ row_ptr, int NB, int N, int E, int cap)
{
    __shared__ int sh[NBMAX];
    int t = threadIdx.x;
    int c = (t < NB) ? min(cursor[t] - t * cap, cap) : 0;
    sh[t] = c;
    __syncthreads();
    for (int off = 1; off < NBMAX; off <<= 1) {
        int v = (t >= off) ? sh[t - off] : 0;
        __syncthreads();
        sh[t] += v;
        __syncthreads();
    }
    if (t < NB) bucket_ptr[t] = sh[t] - c;   // exclusive prefix
    if (t == 0) row_ptr[N] = E;
}

// ------- fused per-bucket: fine CSR + src hist + PRE-SCALED feat convert ---
__global__ __launch_bounds__(256) void fine_place_kernel(
    const int* __restrict__ packed, const u8* __restrict__ sbytes,
    const int* __restrict__ cursor_d, const int* __restrict__ cursor_s,
    const int* __restrict__ bucket_ptr, int* __restrict__ row_ptr,
    float* __restrict__ norm_dst, float* __restrict__ norm_src,
    int* __restrict__ col,
    const float* __restrict__ feat, u16* __restrict__ feat_bf,
    int N, int cap)
{
    __shared__ int lcnt[BSIZE];
    __shared__ int lptr[BSIZE];
    __shared__ uint hist[BSIZE];
    int b = blockIdx.x, t = threadIdx.x;
    int nbase = b << BSHIFT;
    int pbase = b * cap;
    int cnt   = min(cursor_d[b] - pbase, cap);
    int scnt  = min(cursor_s[b] - pbase, cap);
    int obase = bucket_ptr[b];
    lcnt[t] = 0;
    hist[t] = 0;
    __syncthreads();
    for (int i = t; i < cnt; i += 256)
        atomicAdd(&lcnt[packed[pbase + i] >> SRCBITS], 1);
    // src-degree histogram from byte bucket (uint4-packed reads)
    {
        const uint* w = (const uint*)(sbytes + pbase);  // cap mult of 1024 -> aligned
        int nw = scnt >> 2;
        for (int i = t; i < nw; i += 256) {
            uint v = w[i];
            atomicAdd(&hist[v & 255u], 1u);
            atomicAdd(&hist[(v >> 8) & 255u], 1u);
            atomicAdd(&hist[(v >> 16) & 255u], 1u);
            atomicAdd(&hist[v >> 24], 1u);
        }
        for (int i = (nw << 2) + t; i < scnt; i += 256)
            atomicAdd(&hist[sbytes[pbase + i]], 1u);
    }
    __syncthreads();
    for (int off = 1; off < BSIZE; off <<= 1) {
        int v = (t >= off) ? lcnt[t - off] : 0;
        __syncthreads();
        lcnt[t] += v;
        __syncthreads();
    }
    {
        int incl = lcnt[t];
        int excl = (t == 0) ? 0 : lcnt[t - 1];
        int node = nbase + t;
        if (node < N) {
            row_ptr[node] = obase + excl;
            norm_dst[node] = rsqrtf((float)max(incl - excl, 1));
            norm_src[node] = rsqrtf((float)max((int)hist[t], 1));
        }
        lptr[t] = obase + excl;
    }
    __syncthreads();
    for (int i = t; i < cnt; i += 256) {
        int p = packed[pbase + i];
        int slot = atomicAdd(&lptr[p >> SRCBITS], 1);
        col[slot] = p & SRCMASK;
    }
    // ---- feature fp32 -> bf16, pre-scaled by norm_src (hist is local) ----
    {
        const float4* f4 = (const float4*)feat;
        for (int e = t; e < BSIZE * 32; e += 256) {
            int row = e >> 5;
            int node = nbase + row;
            if (node < N) {
                float ns = rsqrtf((float)max((int)hist[row], 1));
                float4 v = f4[(size_t)node * 32 + (e & 31)];
                ushort4 o;
                o.x = f2bf(v.x * ns); o.y = f2bf(v.y * ns);
                o.z = f2bf(v.z * ns); o.w = f2bf(v.w * ns);
                ((ushort4*)feat_bf)[(size_t)node * 32 + (e & 31)] = o;
            }
        }
    }
}

// ---------- FUSED: gather-aggregate -> LDS -> MFMA GEMM -> relu(out) -------
// Empirically-best configuration (r7: 84.0/84.3us dispatches, occ 72%,
// VGPR 32). Inputs pre-scaled by norm_src -> pure row-sum gather, 4 loads
// in flight. Static 4-nodes-per-wave (dynamic queue measured neutral-worse,
// r12). Block barrier retained (all removal variants measured worse, r8/r9).
// bf16 out: LDS-union coalesced epilogue pre-scaled by norm_src; f32 out:
// direct stores (full-tile coverage merges in L2, proven r3/r7).
template <bool BF16_OUT>
__global__ __launch_bounds__(256) void agg_gemm_kernel(
    const u16* __restrict__ hs, const int* __restrict__ row_ptr,
    const int* __restrict__ col, const float* __restrict__ norm_src,
    const float* __restrict__ norm_dst, const u16* __restrict__ WT,
    const float* __restrict__ bias, float* __restrict__ out_f,
    u16* __restrict__ out_b, int N)
{
    __shared__ __align__(16) char smem[16 * 132 * 4];   // 8448B union
    u16   (*rows)[140] = (u16 (*)[140])smem;            // live in gather+MFMA
    float (*outt)[132] = (float (*)[132])smem;          // live in bf16 epilogue
    int wave = threadIdx.x >> 6;
    int lane = threadIdx.x & 63;
    int g    = lane >> 4;     // edge-group 0..3 (gather); quad (MFMA)
    int l16  = lane & 15;     // row position (gather); m16 (MFMA)
    int nbase = blockIdx.x * 16;
    const uint4* h4 = (const uint4*)hs;

    // ---- gather phase: each wave sums 4 nodes' pre-scaled rows ------------
    #pragma unroll
    for (int j = 0; j < 4; ++j) {
        int n = nbase + wave * 4 + j;
        float acc[8];
        #pragma unroll
        for (int k = 0; k < 8; ++k) acc[k] = 0.f;

        if (n < N) {
            int beg = row_ptr[n], end = row_ptr[n + 1];
            int i = beg + g;
            for (; i + 12 < end; i += 16) {       // 4 rows in flight
                int s0 = col[i], s1 = col[i + 4], s2 = col[i + 8], s3 = col[i + 12];
                uint4 v0 = h4[(size_t)s0 * 16 + l16];
                uint4 v1 = h4[(size_t)s1 * 16 + l16];
                uint4 v2 = h4[(size_t)s2 * 16 + l16];
                uint4 v3 = h4[(size_t)s3 * 16 + l16];
                add8(acc, v0); add8(acc, v1); add8(acc, v2); add8(acc, v3);
            }
            for (; i + 4 < end; i += 8) {         // 2 rows in flight
                int s0 = col[i], s1 = col[i + 4];
                uint4 v0 = h4[(size_t)s0 * 16 + l16];
                uint4 v1 = h4[(size_t)s1 * 16 + l16];
                add8(acc, v0); add8(acc, v1);
            }
            if (i < end) {
                int s = col[i];
                uint4 v = h4[(size_t)s * 16 + l16];
                add8(acc, v);
            }
        }

        #pragma unroll
        for (int k = 0; k < 8; ++k) {
            acc[k] += __shfl_xor(acc[k], 16, 64);
            acc[k] += __shfl_xor(acc[k], 32, 64);
        }

        if (g == 0) {
            float nd = (n < N) ? norm_dst[n] : 0.f;
            ushort4 lo, hi;
            lo.x = f2bf(acc[0] * nd); lo.y = f2bf(acc[1] * nd);
            lo.z = f2bf(acc[2] * nd); lo.w = f2bf(acc[3] * nd);
            hi.x = f2bf(acc[4] * nd); hi.y = f2bf(acc[5] * nd);
            hi.z = f2bf(acc[6] * nd); hi.w = f2bf(acc[7] * nd);
            ushort4* o = (ushort4*)&rows[wave * 4 + j][l16 * 8];
            o[0] = lo; o[1] = hi;
        }
    }
    __syncthreads();

    // ---- MFMA phase: wave handles col-tiles c0,c1 (W from global/L2) ------
    int m16 = l16, quad = g;
    int c0 = wave * 2, c1 = wave * 2 + 1;
    floatx4 accm0 = (floatx4){0.f, 0.f, 0.f, 0.f};
    floatx4 accm1 = (floatx4){0.f, 0.f, 0.f, 0.f};
    #pragma unroll
    for (int q = 0; q < 4; ++q) {
        short8 a = *(const short8*)&rows[m16][q * 32 + quad * 8];
        short8 b0 = *(const short8*)(WT + (size_t)(c0 * 16 + m16) * D + q * 32 + quad * 8);
        short8 b1 = *(const short8*)(WT + (size_t)(c1 * 16 + m16) * D + q * 32 + quad * 8);
        accm0 = __builtin_amdgcn_mfma_f32_16x16x32_bf16(a, b0, accm0, 0, 0, 0);
        accm1 = __builtin_amdgcn_mfma_f32_16x16x32_bf16(a, b1, accm1, 0, 0, 0);
    }
    float bv0 = bias[c0 * 16 + m16];
    float bv1 = bias[c1 * 16 + m16];

    if (BF16_OUT) {
        __syncthreads();   // all rows-reads done; safe to overwrite union
        #pragma unroll
        for (int r = 0; r < 4; ++r) {
            outt[quad * 4 + r][c0 * 16 + m16] = fmaxf(accm0[r] + bv0, 0.f);
            outt[quad * 4 + r][c1 * 16 + m16] = fmaxf(accm1[r] + bv1, 0.f);
        }
        __syncthreads();
        // coalesced 4KB burst; pre-scale by norm_src for next layer's gather
        int t = threadIdx.x;
        int r = t >> 4, c = (t & 15) * 8;
        if (nbase + r < N) {
            float ns = norm_src[nbase + r];
            ushort4 o0, o1;
            o0.x = f2bf(outt[r][c + 0] * ns); o0.y = f2bf(outt[r][c + 1] * ns);
            o0.z = f2bf(outt[r][c + 2] * ns); o0.w = f2bf(outt[r][c + 3] * ns);
            o1.x = f2bf(outt[r][c + 4] * ns); o1.y = f2bf(outt[r][c + 5] * ns);
            o1.z = f2bf(outt[r][c + 6] * ns); o1.w = f2bf(outt[r][c + 7] * ns);
            ushort4* o = (ushort4*)(out_b + (size_t)(nbase + r) * D + c);
            o[0] = o0; o[1] = o1;
        }
    } else {
        // direct stores: full 16x128 f32 tile covered per block -> L2 merges
        #pragma unroll
        for (int r = 0; r < 4; ++r) {
            int row = nbase + quad * 4 + r;
            if (row < N) {
                out_f[(size_t)row * D + c0 * 16 + m16] = fmaxf(accm0[r] + bv0, 0.f);
                out_f[(size_t)row * D + c1 * 16 + m16] = fmaxf(accm1[r] + bv1, 0.f);
            }
        }
    }
}

extern "C" void kernel_launch(void* const* d_in, const int* in_sizes, int n_in,
                              void* d_out, int out_size, void* d_ws, size_t ws_size,
                              hipStream_t stream)
{
    const float* features = (const float*)d_in[0];
    const int*   src      = (const int*)d_in[1];
    const int*   dst      = (const int*)d_in[2];
    const float* W1       = (const float*)d_in[3];
    const float* b1       = (const float*)d_in[4];
    const float* W2       = (const float*)d_in[5];
    const float* b2       = (const float*)d_in[6];
    float*       out      = (float*)d_out;

    const int N = in_sizes[0] / D;
    const int E = in_sizes[1];
    const int NB = (N + BSIZE - 1) >> BSHIFT;

    // padded bucket capacity: 2x mean, multiple of 1024;
    // bounded so packed(4B) + sbytes(1B) fit the N*D bf16 region (5B/slot).
    int cap = ((2 * (E / NB) + 2047) / 1024) * 1024;
    int cap_max = (int)(((size_t)N * D * 2 / (5 * NB)) / 1024 * 1024);
    if (cap > cap_max) cap = cap_max;

    // workspace layout
    u16*   scratch  = (u16*)d_ws;                   // N*D bf16 region (packed+sbytes)
    int*   packed   = (int*)scratch;                // NB*cap ints
    u8*    sbytes   = (u8*)(packed + (size_t)NB * cap);  // NB*cap bytes
    u16*   feat_bf  = scratch + (size_t)N * D;      // N*D bf16
    u16*   hs_bf    = feat_bf + (size_t)N * D;      // N*D bf16
    u16*   wT1      = hs_bf + (size_t)N * D;        // 16384 bf16
    u16*   wT2      = wT1 + D * D;                  // 16384 bf16
    float* norm_src = (float*)(wT2 + D * D);        // N
    float* norm_dst = norm_src + N;                 // N
    int*   iws          = (int*)(norm_dst + N);
    int*   row_ptr      = iws;                      // N+1
    int*   col          = row_ptr + N + 1;          // E
    int*   bucket_ptr   = col + E;                  // NBMAX+1
    int*   cursor_d     = bucket_ptr + NBMAX + 1;   // NBMAX
    int*   cursor_s     = cursor_d + NBMAX;         // NBMAX

    const int ebk = (E + CHUNK - 1) / CHUNK;
    const int fuse_blocks = (N + 15) / 16;

    // ---- CSR build: 4 launches total before the fused layers ----
    setup_kernel<<<129, 256, 0, stream>>>(W1, W2, wT1, wT2, cursor_d, cursor_s, NB, cap);
    scatter_direct_kernel<<<ebk, 256, 0, stream>>>(src, dst, cursor_d, cursor_s, packed, sbytes, E, cap);
    bucket_scan_kernel<<<1, NBMAX, 0, stream>>>(cursor_d, bucket_ptr, row_ptr, NB, N, E, cap);
    fine_place_kernel<<<NB, 256, 0, stream>>>(
        packed, sbytes, cursor_d, cursor_s, bucket_ptr, row_ptr,
        norm_dst, norm_src, col, features, feat_bf, N, cap);

    // ---- layer 1 (fused aggregate+GEMM, bf16 out pre-scaled by norm_src) ----
    agg_gemm_kernel<true><<<fuse_blocks, 256, 0, stream>>>(
        feat_bf, row_ptr, col, norm_src, norm_dst, wT1, b1, nullptr, hs_bf, N);

    // ---- layer 2 (fused aggregate+GEMM, f32 out) ----
    agg_gemm_kernel<false><<<fuse_blocks, 256, 0, stream>>>(
        hs_bf, row_ptr, col, norm_src, norm_dst, wT2, b2, out, nullptr, N);
}